// Round 1
// baseline (693.353 us; speedup 1.0000x reference)
//
#include <hip/hip_runtime.h>

// ---------------------------------------------------------------------------
// GCN: out = agg(relu(agg(relu(agg(x)W0+b0))W1+b1) @ W2) + b2
// using agg(hW) == agg(h)W  (aggregation is linear).
// CSR-by-dst built on device each call; node-parallel gather aggregation.
// ---------------------------------------------------------------------------

__device__ __forceinline__ int edge_at(const void* ei, int is64, long long pos) {
  if (is64) return (int)((const long long*)ei)[pos];
  return ((const int*)ei)[pos];
}

// Detect whether edge_index is stored as int64 on device:
// if int64 with values < 2^31, every odd int32 slot is 0.
__global__ void k_detect(const int* __restrict__ ei32, int* __restrict__ flag) {
  int tid = threadIdx.x;                       // 64 threads, one wave
  int v = ei32[2 * tid + 1];
  unsigned long long m = __ballot(v != 0);
  if (tid == 0) flag[0] = (m == 0ull) ? 1 : 0; // all-zero odd slots -> int64
}

__global__ void k_zero(int* __restrict__ p, int n) {
  int i = blockIdx.x * blockDim.x + threadIdx.x;
  if (i < n) p[i] = 0;
}

__global__ void k_hist(const void* __restrict__ ei, const int* __restrict__ flag,
                       int E, int* __restrict__ counts) {
  int e = blockIdx.x * blockDim.x + threadIdx.x;
  if (e >= E) return;
  int is64 = flag[0];
  int d = edge_at(ei, is64, (long long)E + e);
  atomicAdd(&counts[d], 1);
}

__global__ void k_scan_a(const int* __restrict__ counts, int* __restrict__ lscan,
                         int* __restrict__ partials, int n) {
  __shared__ int sm[256];
  int tid = threadIdx.x;
  int i = blockIdx.x * 256 + tid;
  int v = (i < n) ? counts[i] : 0;
  sm[tid] = v;
  __syncthreads();
  for (int off = 1; off < 256; off <<= 1) {
    int t = (tid >= off) ? sm[tid - off] : 0;
    __syncthreads();
    sm[tid] += t;
    __syncthreads();
  }
  if (i < n) lscan[i] = sm[tid];
  if (tid == 255) partials[blockIdx.x] = sm[255];
}

__global__ void k_scan_b(int* __restrict__ partials, int nb) {
  __shared__ int sm[512];
  int tid = threadIdx.x;
  int v = (tid < nb) ? partials[tid] : 0;
  sm[tid] = v;
  __syncthreads();
  for (int off = 1; off < 512; off <<= 1) {
    int t = (tid >= off) ? sm[tid - off] : 0;
    __syncthreads();
    sm[tid] += t;
    __syncthreads();
  }
  if (tid < nb) partials[tid] = sm[tid] - v;   // exclusive
}

__global__ void k_scan_c(const int* __restrict__ lscan, const int* __restrict__ counts,
                         const int* __restrict__ partials, int* __restrict__ rowptr,
                         int* __restrict__ cursor, int n, int E) {
  int i = blockIdx.x * 256 + threadIdx.x;
  if (i >= n) return;
  int rp = lscan[i] - counts[i] + partials[blockIdx.x];
  rowptr[i] = rp;
  cursor[i] = rp;
  if (i == n - 1) rowptr[n] = E;
}

__global__ void k_fill(const void* __restrict__ ei, const int* __restrict__ flag,
                       int E, int* __restrict__ cursor, int* __restrict__ colsrc) {
  int e = blockIdx.x * blockDim.x + threadIdx.x;
  if (e >= E) return;
  int is64 = flag[0];
  int d = edge_at(ei, is64, (long long)E + e);
  int s = edge_at(ei, is64, e);
  int pos = atomicAdd(&cursor[d], 1);
  colsrc[pos] = s;
}

// out[n][f] = sum over in-edges(n) of H[src][f]   (128 feats, 1 block/node)
__global__ void k_agg128(const float* __restrict__ H, const int* __restrict__ rowptr,
                         const int* __restrict__ colsrc, float* __restrict__ out) {
  int n = blockIdx.x;
  int f = threadIdx.x;
  int beg = rowptr[n], end = rowptr[n + 1];
  float acc = 0.f;
  int e = beg;
  for (; e + 3 < end; e += 4) {
    int s0 = colsrc[e], s1 = colsrc[e + 1], s2 = colsrc[e + 2], s3 = colsrc[e + 3];
    float v0 = H[(size_t)s0 * 128 + f];
    float v1 = H[(size_t)s1 * 128 + f];
    float v2 = H[(size_t)s2 * 128 + f];
    float v3 = H[(size_t)s3 * 128 + f];
    acc += (v0 + v1) + (v2 + v3);
  }
  for (; e < end; ++e) acc += H[(size_t)colsrc[e] * 128 + f];
  out[(size_t)n * 128 + f] = acc;
}

// 40-wide aggregation with post-aggregation bias (layer 3)
__global__ void k_agg40(const float* __restrict__ H, const int* __restrict__ rowptr,
                        const int* __restrict__ colsrc, const float* __restrict__ bias,
                        float* __restrict__ out) {
  int n = blockIdx.x;
  int f = threadIdx.x;                          // 64 threads, 40 active
  if (f >= 40) return;
  int beg = rowptr[n], end = rowptr[n + 1];
  float acc = 0.f;
  int e = beg;
  for (; e + 3 < end; e += 4) {
    int s0 = colsrc[e], s1 = colsrc[e + 1], s2 = colsrc[e + 2], s3 = colsrc[e + 3];
    acc += (H[(size_t)s0 * 40 + f] + H[(size_t)s1 * 40 + f]) +
           (H[(size_t)s2 * 40 + f] + H[(size_t)s3 * 40 + f]);
  }
  for (; e < end; ++e) acc += H[(size_t)colsrc[e] * 40 + f];
  out[(size_t)n * 40 + f] = acc + bias[f];
}

// C[N,F] = act(A[N,128] @ W[128,F] + bias); tile 64 rows x 64 cols, K=128.
__global__ __launch_bounds__(256) void k_gemm(const float* __restrict__ A,
                                              const float* __restrict__ W,
                                              const float* __restrict__ bias,
                                              float* __restrict__ C,
                                              int N, int F, int relu) {
  __shared__ float As[64 * 128];   // 32 KB
  __shared__ float Ws[128 * 64];   // 32 KB
  int tid = threadIdx.x;
  int row0 = blockIdx.x * 64;
  int cb = blockIdx.y * 64;

  // stage A tile: 64 rows x 128 k  (2048 float4s / 256 threads = 8 each)
  #pragma unroll
  for (int j = 0; j < 8; ++j) {
    int f4 = tid + j * 256;
    int r = f4 >> 5, c4 = f4 & 31;
    int gr = row0 + r;
    float4 v = make_float4(0.f, 0.f, 0.f, 0.f);
    if (gr < N) v = *reinterpret_cast<const float4*>(A + (size_t)gr * 128 + c4 * 4);
    *reinterpret_cast<float4*>(&As[r * 128 + c4 * 4]) = v;
  }
  // stage W tile: 128 k x 64 cols
  #pragma unroll
  for (int j = 0; j < 8; ++j) {
    int f4 = tid + j * 256;
    int k = f4 >> 4, c4 = f4 & 15;
    int gc = cb + c4 * 4;
    float4 v = make_float4(0.f, 0.f, 0.f, 0.f);
    if (gc + 3 < F) v = *reinterpret_cast<const float4*>(W + (size_t)k * F + gc);
    *reinterpret_cast<float4*>(&Ws[k * 64 + c4 * 4]) = v;
  }
  __syncthreads();

  int ty = tid >> 4, tx = tid & 15;            // 16x16 threads, 4x4 regs each
  float acc[4][4] = {};
  #pragma unroll 4
  for (int k4 = 0; k4 < 32; ++k4) {
    float a[4][4], w[4][4];
    #pragma unroll
    for (int i = 0; i < 4; ++i) {
      float4 t = *reinterpret_cast<const float4*>(&As[(ty * 4 + i) * 128 + k4 * 4]);
      a[i][0] = t.x; a[i][1] = t.y; a[i][2] = t.z; a[i][3] = t.w;
    }
    #pragma unroll
    for (int j = 0; j < 4; ++j) {
      float4 t = *reinterpret_cast<const float4*>(&Ws[(k4 * 4 + j) * 64 + tx * 4]);
      w[j][0] = t.x; w[j][1] = t.y; w[j][2] = t.z; w[j][3] = t.w;
    }
    #pragma unroll
    for (int j = 0; j < 4; ++j)
      #pragma unroll
      for (int i = 0; i < 4; ++i)
        #pragma unroll
        for (int c = 0; c < 4; ++c)
          acc[i][c] = fmaf(a[i][j], w[j][c], acc[i][c]);
  }

  #pragma unroll
  for (int i = 0; i < 4; ++i) {
    int gr = row0 + ty * 4 + i;
    if (gr >= N) continue;
    #pragma unroll
    for (int c = 0; c < 4; ++c) {
      int gc = cb + tx * 4 + c;
      if (gc >= F) continue;
      float v = acc[i][c] + (bias ? bias[gc] : 0.f);
      if (relu) v = fmaxf(v, 0.f);
      C[(size_t)gr * F + gc] = v;
    }
  }
}

extern "C" void kernel_launch(void* const* d_in, const int* in_sizes, int n_in,
                              void* d_out, int out_size, void* d_ws, size_t ws_size,
                              hipStream_t stream) {
  const float* x  = (const float*)d_in[0];
  const void*  ei = d_in[1];
  const float* W0 = (const float*)d_in[2];
  const float* b0 = (const float*)d_in[3];
  const float* W1 = (const float*)d_in[4];
  const float* b1 = (const float*)d_in[5];
  const float* W2 = (const float*)d_in[6];
  const float* b2 = (const float*)d_in[7];
  float* out = (float*)d_out;

  const int N = in_sizes[0] / 128;   // 100000
  const int E = in_sizes[1] / 2;     // 1600000

  char* wp = (char*)d_ws;
  auto alloc = [&](size_t bytes) -> void* {
    void* p = (void*)wp;
    wp += (bytes + 255) & ~(size_t)255;
    return p;
  };
  float* bufA   = (float*)alloc((size_t)N * 128 * sizeof(float));  // 51.2 MB
  float* bufH   = (float*)alloc((size_t)N * 128 * sizeof(float));  // 51.2 MB
  int* colsrc   = (int*)alloc((size_t)E * sizeof(int));            // 6.4 MB
  int* rowptr   = (int*)alloc((size_t)(N + 1) * sizeof(int));
  int* counts   = (int*)alloc((size_t)N * sizeof(int));
  int* cursor   = (int*)alloc((size_t)N * sizeof(int));
  int* lscan    = (int*)alloc((size_t)N * sizeof(int));
  int* partials = (int*)alloc(4096);
  int* flag     = (int*)alloc(256);

  int nb = (N + 255) / 256;          // 391 (<= 512 for scan_b)
  int eb = (E + 255) / 256;

  // CSR build (by destination)
  k_detect<<<1, 64, 0, stream>>>((const int*)ei, flag);
  k_zero<<<nb, 256, 0, stream>>>(counts, N);
  k_hist<<<eb, 256, 0, stream>>>(ei, flag, E, counts);
  k_scan_a<<<nb, 256, 0, stream>>>(counts, lscan, partials, N);
  k_scan_b<<<1, 512, 0, stream>>>(partials, nb);
  k_scan_c<<<nb, 256, 0, stream>>>(lscan, counts, partials, rowptr, cursor, N, E);
  k_fill<<<eb, 256, 0, stream>>>(ei, flag, E, cursor, colsrc);

  dim3 g128((N + 63) / 64, 2), g40((N + 63) / 64, 1);

  // layer 1: A1 = agg(x); h1 = relu(A1 @ W0 + b0)
  k_agg128<<<N, 128, 0, stream>>>(x, rowptr, colsrc, bufA);
  k_gemm<<<g128, 256, 0, stream>>>(bufA, W0, b0, bufH, N, 128, 1);
  // layer 2: A2 = agg(h1); h2 = relu(A2 @ W1 + b1)
  k_agg128<<<N, 128, 0, stream>>>(bufH, rowptr, colsrc, bufA);
  k_gemm<<<g128, 256, 0, stream>>>(bufA, W1, b1, bufH, N, 128, 1);
  // layer 3: t3 = h2 @ W2 (no bias); out = agg40(t3) + b2
  k_gemm<<<g40, 256, 0, stream>>>(bufH, W2, nullptr, bufA, N, 40, 0);
  k_agg40<<<N, 64, 0, stream>>>(bufA, rowptr, colsrc, b2, out);
}

// Round 2
// 412.793 us; speedup vs baseline: 1.6797x; 1.6797x over previous
//
#include <hip/hip_runtime.h>

// ---------------------------------------------------------------------------
// GCN: out = agg(relu(agg(relu(agg(x)W0+b0))W1+b1) @ W2) + b2
//   (aggregation commutes with the linear transform)
// R2: rank-based atomic-free fill; bf16 feature storage (f32 accum);
//     MFMA bf16 GEMMs with pre-transposed bf16 weights.
// ---------------------------------------------------------------------------

typedef short bf16x8 __attribute__((ext_vector_type(8)));
typedef float f32x4  __attribute__((ext_vector_type(4)));

__device__ __forceinline__ float bflo(unsigned int v) {
  union { float f; unsigned int i; } w; w.i = v << 16; return w.f;
}
__device__ __forceinline__ float bfhi(unsigned int v) {
  union { float f; unsigned int i; } w; w.i = v & 0xffff0000u; return w.f;
}
__device__ __forceinline__ unsigned short f2bf(float f) {
  union { float f; unsigned int i; } w; w.f = f;
  unsigned int b = w.i;
  unsigned int r = (b + 0x7fffu + ((b >> 16) & 1u)) >> 16;   // RNE
  return (unsigned short)r;
}

__device__ __forceinline__ int edge_at(const void* ei, int is64, long long pos) {
  if (is64) return (int)((const long long*)ei)[pos];
  return ((const int*)ei)[pos];
}

// int64-on-device detection: odd int32 slots all zero across 64 samples.
__global__ void k_detect(const int* __restrict__ ei32, int* __restrict__ flag) {
  int tid = threadIdx.x;
  int v = ei32[2 * tid + 1];
  unsigned long long m = __ballot(v != 0);
  if (tid == 0) flag[0] = (m == 0ull) ? 1 : 0;
}

__global__ void k_zero(int* __restrict__ p, int n) {
  int i = blockIdx.x * blockDim.x + threadIdx.x;
  if (i < n) p[i] = 0;
}

// f32 -> bf16 (4 elems/thread)
__global__ void k_cvt(const float* __restrict__ in, unsigned short* __restrict__ out,
                      long long n4) {
  long long i = (long long)blockIdx.x * blockDim.x + threadIdx.x;
  if (i >= n4) return;
  float4 v = *reinterpret_cast<const float4*>(in + i * 4);
  ushort4 o;
  o.x = f2bf(v.x); o.y = f2bf(v.y); o.z = f2bf(v.z); o.w = f2bf(v.w);
  *reinterpret_cast<ushort4*>(out + i * 4) = o;
}

// Wt[c][k] = bf16(W[k][c]); pad cols F..Fp-1 with zero. K=128.
__global__ void k_wt(const float* __restrict__ W, unsigned short* __restrict__ Wt,
                     int F, int Fp) {
  int idx = blockIdx.x * blockDim.x + threadIdx.x;
  if (idx >= Fp * 128) return;
  int c = idx >> 7, k = idx & 127;
  Wt[c * 128 + k] = (c < F) ? f2bf(W[(size_t)k * F + c]) : (unsigned short)0;
}

__global__ void k_hist_rank(const void* __restrict__ ei, const int* __restrict__ flag,
                            int E, int* __restrict__ counts, int* __restrict__ rank) {
  int e = blockIdx.x * blockDim.x + threadIdx.x;
  if (e >= E) return;
  int d = edge_at(ei, flag[0], (long long)E + e);
  rank[e] = atomicAdd(&counts[d], 1);
}

__global__ void k_scan_a(const int* __restrict__ counts, int* __restrict__ lscan,
                         int* __restrict__ partials, int n) {
  __shared__ int sm[256];
  int tid = threadIdx.x;
  int i = blockIdx.x * 256 + tid;
  int v = (i < n) ? counts[i] : 0;
  sm[tid] = v;
  __syncthreads();
  for (int off = 1; off < 256; off <<= 1) {
    int t = (tid >= off) ? sm[tid - off] : 0;
    __syncthreads();
    sm[tid] += t;
    __syncthreads();
  }
  if (i < n) lscan[i] = sm[tid];
  if (tid == 255) partials[blockIdx.x] = sm[255];
}

__global__ void k_scan_b(int* __restrict__ partials, int nb) {
  __shared__ int sm[512];
  int tid = threadIdx.x;
  int v = (tid < nb) ? partials[tid] : 0;
  sm[tid] = v;
  __syncthreads();
  for (int off = 1; off < 512; off <<= 1) {
    int t = (tid >= off) ? sm[tid - off] : 0;
    __syncthreads();
    sm[tid] += t;
    __syncthreads();
  }
  if (tid < nb) partials[tid] = sm[tid] - v;   // exclusive
}

__global__ void k_scan_c(const int* __restrict__ lscan, const int* __restrict__ counts,
                         const int* __restrict__ partials, int* __restrict__ rowptr,
                         int n, int E) {
  int i = blockIdx.x * 256 + threadIdx.x;
  if (i >= n) return;
  rowptr[i] = lscan[i] - counts[i] + partials[blockIdx.x];
  if (i == n - 1) rowptr[n] = E;
}

// atomic-free fill: pos = rowptr[d] + rank[e]
__global__ void k_fill(const void* __restrict__ ei, const int* __restrict__ flag,
                       int E, const int* __restrict__ rowptr, const int* __restrict__ rank,
                       int* __restrict__ colsrc) {
  int e = blockIdx.x * blockDim.x + threadIdx.x;
  if (e >= E) return;
  int is64 = flag[0];
  int d = edge_at(ei, is64, (long long)E + e);
  int s = edge_at(ei, is64, e);
  colsrc[rowptr[d] + rank[e]] = s;
}

// 128-wide bf16 aggregation: 1 wave/node, lane holds 2 feats. 4 nodes/block.
__global__ void k_agg128b(const unsigned int* __restrict__ H,
                          const int* __restrict__ rowptr, const int* __restrict__ colsrc,
                          unsigned int* __restrict__ out, int N) {
  int node = blockIdx.x * 4 + (threadIdx.x >> 6);
  if (node >= N) return;
  int l = threadIdx.x & 63;
  int beg = rowptr[node], end = rowptr[node + 1];
  float a0 = 0.f, a1 = 0.f;
  int e = beg;
  for (; e + 3 < end; e += 4) {
    int s0 = colsrc[e], s1 = colsrc[e + 1], s2 = colsrc[e + 2], s3 = colsrc[e + 3];
    unsigned int v0 = H[(size_t)s0 * 64 + l];
    unsigned int v1 = H[(size_t)s1 * 64 + l];
    unsigned int v2 = H[(size_t)s2 * 64 + l];
    unsigned int v3 = H[(size_t)s3 * 64 + l];
    a0 += (bflo(v0) + bflo(v1)) + (bflo(v2) + bflo(v3));
    a1 += (bfhi(v0) + bfhi(v1)) + (bfhi(v2) + bfhi(v3));
  }
  for (; e < end; ++e) {
    unsigned int v = H[(size_t)colsrc[e] * 64 + l];
    a0 += bflo(v); a1 += bfhi(v);
  }
  out[(size_t)node * 64 + l] = ((unsigned int)f2bf(a1) << 16) | f2bf(a0);
}

// 40-wide final aggregation from padded [N][48] bf16; out f32 [N][40] + b2.
__global__ void k_agg40(const unsigned int* __restrict__ T,
                        const int* __restrict__ rowptr, const int* __restrict__ colsrc,
                        const float* __restrict__ b2, float* __restrict__ out, int N) {
  int node = blockIdx.x * 4 + (threadIdx.x >> 6);
  if (node >= N) return;
  int l = threadIdx.x & 63;
  if (l >= 20) return;                       // 20 lanes x 2 feats = 40
  int beg = rowptr[node], end = rowptr[node + 1];
  float a0 = 0.f, a1 = 0.f;
  int e = beg;
  for (; e + 3 < end; e += 4) {
    int s0 = colsrc[e], s1 = colsrc[e + 1], s2 = colsrc[e + 2], s3 = colsrc[e + 3];
    unsigned int v0 = T[(size_t)s0 * 24 + l];
    unsigned int v1 = T[(size_t)s1 * 24 + l];
    unsigned int v2 = T[(size_t)s2 * 24 + l];
    unsigned int v3 = T[(size_t)s3 * 24 + l];
    a0 += (bflo(v0) + bflo(v1)) + (bflo(v2) + bflo(v3));
    a1 += (bfhi(v0) + bfhi(v1)) + (bfhi(v2) + bfhi(v3));
  }
  for (; e < end; ++e) {
    unsigned int v = T[(size_t)colsrc[e] * 24 + l];
    a0 += bflo(v); a1 += bfhi(v);
  }
  float2 o;
  o.x = a0 + b2[2 * l];
  o.y = a1 + b2[2 * l + 1];
  *reinterpret_cast<float2*>(out + (size_t)node * 40 + 2 * l) = o;
}

// C[N][Fp] = act(A[N][128] @ W + bias) in bf16. Wt is [Fp][128] bf16 transposed.
// 4 waves/block, 16 rows/wave, LDS-free. MFMA 16x16x32 bf16.
__global__ __launch_bounds__(256) void k_gemm(const unsigned short* __restrict__ A,
                                              const unsigned short* __restrict__ Wt,
                                              const float* __restrict__ bias,
                                              unsigned short* __restrict__ C,
                                              int N, int Fp, int relu) {
  int tid = threadIdx.x;
  int w = tid >> 6, l = tid & 63;
  int r0 = blockIdx.x * 64 + w * 16;
  int arow = r0 + (l & 15);
  if (arow >= N) arow = N - 1;               // clamp; OOB rows masked at store
  int kk = (l >> 4) * 8;
  bf16x8 a[4];
  #pragma unroll
  for (int ks = 0; ks < 4; ++ks)
    a[ks] = *reinterpret_cast<const bf16x8*>(A + (size_t)arow * 128 + ks * 32 + kk);

  int crow0 = r0 + (l >> 4) * 4;
  int ccol = l & 15;
  for (int cf = 0; cf < Fp / 16; ++cf) {
    f32x4 acc = {0.f, 0.f, 0.f, 0.f};
    const unsigned short* wp = Wt + (size_t)(cf * 16 + ccol) * 128 + kk;
    #pragma unroll
    for (int ks = 0; ks < 4; ++ks) {
      bf16x8 b = *reinterpret_cast<const bf16x8*>(wp + ks * 32);
      acc = __builtin_amdgcn_mfma_f32_16x16x32_bf16(a[ks], b, acc, 0, 0, 0);
    }
    float bv = bias ? bias[cf * 16 + ccol] : 0.f;
    #pragma unroll
    for (int r = 0; r < 4; ++r) {
      int gr = crow0 + r;
      if (gr >= N) continue;
      float v = acc[r] + bv;
      if (relu) v = fmaxf(v, 0.f);
      C[(size_t)gr * Fp + cf * 16 + ccol] = f2bf(v);
    }
  }
}

extern "C" void kernel_launch(void* const* d_in, const int* in_sizes, int n_in,
                              void* d_out, int out_size, void* d_ws, size_t ws_size,
                              hipStream_t stream) {
  const float* x  = (const float*)d_in[0];
  const void*  ei = d_in[1];
  const float* W0 = (const float*)d_in[2];
  const float* b0 = (const float*)d_in[3];
  const float* W1 = (const float*)d_in[4];
  const float* b1 = (const float*)d_in[5];
  const float* W2 = (const float*)d_in[6];
  const float* b2 = (const float*)d_in[7];
  float* out = (float*)d_out;

  const int N = in_sizes[0] / 128;     // 100000
  const int E = in_sizes[1] / 2;       // 1600000
  const int FOUT = in_sizes[6] / 128;  // 40
  const int FP3 = 48;                  // padded layer-3 width

  char* wp = (char*)d_ws;
  auto alloc = [&](size_t bytes) -> void* {
    void* p = (void*)wp;
    wp += (bytes + 255) & ~(size_t)255;
    return p;
  };
  unsigned short* xb   = (unsigned short*)alloc((size_t)N * 128 * 2);  // 25.6 MB
  unsigned short* bufA = (unsigned short*)alloc((size_t)N * 128 * 2);  // 25.6 MB
  unsigned short* bufH = (unsigned short*)alloc((size_t)N * 128 * 2);  // 25.6 MB
  unsigned short* t3   = (unsigned short*)alloc((size_t)N * FP3 * 2);  //  9.6 MB
  unsigned short* Wt0  = (unsigned short*)alloc(128 * 128 * 2);
  unsigned short* Wt1  = (unsigned short*)alloc(128 * 128 * 2);
  unsigned short* Wt2  = (unsigned short*)alloc(FP3 * 128 * 2);
  int* colsrc   = (int*)alloc((size_t)E * 4);                          //  6.4 MB
  int* rank     = (int*)alloc((size_t)E * 4);                          //  6.4 MB
  int* rowptr   = (int*)alloc((size_t)(N + 1) * 4);
  int* counts   = (int*)alloc((size_t)N * 4);
  int* lscan    = (int*)alloc((size_t)N * 4);
  int* partials = (int*)alloc(4096);
  int* flag     = (int*)alloc(256);

  int nb = (N + 255) / 256;            // 391 (<=512 for scan_b)
  int eb = (E + 255) / 256;

  k_detect<<<1, 64, 0, stream>>>((const int*)ei, flag);
  // weight prep + x conversion
  long long n4 = (long long)N * 32;
  k_cvt<<<(int)((n4 + 255) / 256), 256, 0, stream>>>(x, xb, n4);
  k_wt<<<(128 * 128 + 255) / 256, 256, 0, stream>>>(W0, Wt0, 128, 128);
  k_wt<<<(128 * 128 + 255) / 256, 256, 0, stream>>>(W1, Wt1, 128, 128);
  k_wt<<<(FP3 * 128 + 255) / 256, 256, 0, stream>>>(W2, Wt2, FOUT, FP3);
  // CSR build (by destination), atomic-free fill via rank
  k_zero<<<nb, 256, 0, stream>>>(counts, N);
  k_hist_rank<<<eb, 256, 0, stream>>>(ei, flag, E, counts, rank);
  k_scan_a<<<nb, 256, 0, stream>>>(counts, lscan, partials, N);
  k_scan_b<<<1, 512, 0, stream>>>(partials, nb);
  k_scan_c<<<nb, 256, 0, stream>>>(lscan, counts, partials, rowptr, N, E);
  k_fill<<<eb, 256, 0, stream>>>(ei, flag, E, rowptr, rank, colsrc);

  int gagg = (N + 3) / 4;
  int ggemm = (N + 63) / 64;
  // layer 1
  k_agg128b<<<gagg, 256, 0, stream>>>((const unsigned int*)xb, rowptr, colsrc,
                                      (unsigned int*)bufA, N);
  k_gemm<<<ggemm, 256, 0, stream>>>(bufA, Wt0, b0, bufH, N, 128, 1);
  // layer 2
  k_agg128b<<<gagg, 256, 0, stream>>>((const unsigned int*)bufH, rowptr, colsrc,
                                      (unsigned int*)bufA, N);
  k_gemm<<<ggemm, 256, 0, stream>>>(bufA, Wt1, b1, bufH, N, 128, 1);
  // layer 3: t3 = h2 @ W2 (padded to 48), then 40-wide agg + b2
  k_gemm<<<ggemm, 256, 0, stream>>>(bufH, Wt2, nullptr, t3, N, FP3, 0);
  k_agg40<<<gagg, 256, 0, stream>>>((const unsigned int*)t3, rowptr, colsrc, b2, out, N);
}

// Round 3
// 321.763 us; speedup vs baseline: 2.1549x; 1.2829x over previous
//
#include <hip/hip_runtime.h>

// ---------------------------------------------------------------------------
// GCN: out = agg(relu(agg(relu(agg(x)W0+b0))W1+b1) @ W2) + b2
// R3: atomic-free CSR via MSD bucket sort (LDS hist -> scan -> scatter ->
//     per-bucket counting sort); 16B-gather aggregation with shfl reduce.
// ---------------------------------------------------------------------------

typedef short bf16x8 __attribute__((ext_vector_type(8)));
typedef float f32x4  __attribute__((ext_vector_type(4)));

#define EPB 4096   // edges per routing block

__device__ __forceinline__ float bflo(unsigned int v) {
  union { float f; unsigned int i; } w; w.i = v << 16; return w.f;
}
__device__ __forceinline__ float bfhi(unsigned int v) {
  union { float f; unsigned int i; } w; w.i = v & 0xffff0000u; return w.f;
}
__device__ __forceinline__ unsigned short f2bf(float f) {
  union { float f; unsigned int i; } w; w.f = f;
  unsigned int b = w.i;
  unsigned int r = (b + 0x7fffu + ((b >> 16) & 1u)) >> 16;   // RNE
  return (unsigned short)r;
}

__device__ __forceinline__ int edge_at(const void* ei, int is64, long long pos) {
  if (is64) return (int)((const long long*)ei)[pos];
  return ((const int*)ei)[pos];
}

// int64-on-device detection: odd int32 slots all zero across 64 samples.
__global__ void k_detect(const int* __restrict__ ei32, int* __restrict__ flag) {
  int tid = threadIdx.x;
  int v = ei32[2 * tid + 1];
  unsigned long long m = __ballot(v != 0);
  if (tid == 0) flag[0] = (m == 0ull) ? 1 : 0;
}

// f32 -> bf16 (4 elems/thread)
__global__ void k_cvt(const float* __restrict__ in, unsigned short* __restrict__ out,
                      long long n4) {
  long long i = (long long)blockIdx.x * blockDim.x + threadIdx.x;
  if (i >= n4) return;
  float4 v = *reinterpret_cast<const float4*>(in + i * 4);
  ushort4 o;
  o.x = f2bf(v.x); o.y = f2bf(v.y); o.z = f2bf(v.z); o.w = f2bf(v.w);
  *reinterpret_cast<ushort4*>(out + i * 4) = o;
}

// Wt[c][k] = bf16(W[k][c]); pad cols F..Fp-1 with zero. K=128.
__global__ void k_wt(const float* __restrict__ W, unsigned short* __restrict__ Wt,
                     int F, int Fp) {
  int idx = blockIdx.x * blockDim.x + threadIdx.x;
  if (idx >= Fp * 128) return;
  int c = idx >> 7, k = idx & 127;
  Wt[c * 128 + k] = (c < F) ? f2bf(W[(size_t)k * F + c]) : (unsigned short)0;
}

// --------------------------- CSR build --------------------------------------
// bhist[bucket][blk] = #edges of this 4096-edge chunk landing in bucket.
__global__ __launch_bounds__(256) void b_hist(const void* __restrict__ ei,
                                              const int* __restrict__ flag, int E,
                                              int* __restrict__ bhist,
                                              int NBKT, int NBLKE) {
  __shared__ int h[512];
  int blk = blockIdx.x, tid = threadIdx.x;
  for (int i = tid; i < NBKT; i += 256) h[i] = 0;
  __syncthreads();
  int is64 = flag[0];
  int base = blk * EPB;
  int cnt = min(EPB, E - base);
  for (int i = tid; i < cnt; i += 256) {
    int d = edge_at(ei, is64, (long long)E + base + i);
    atomicAdd(&h[d >> 8], 1);
  }
  __syncthreads();
  for (int i = tid; i < NBKT; i += 256) bhist[i * NBLKE + blk] = h[i];
}

__global__ void k_scan_a(const int* __restrict__ vals, int* __restrict__ lscan,
                         int* __restrict__ partials, int n) {
  __shared__ int sm[256];
  int tid = threadIdx.x;
  int i = blockIdx.x * 256 + tid;
  int v = (i < n) ? vals[i] : 0;
  sm[tid] = v;
  __syncthreads();
  for (int off = 1; off < 256; off <<= 1) {
    int t = (tid >= off) ? sm[tid - off] : 0;
    __syncthreads();
    sm[tid] += t;
    __syncthreads();
  }
  if (i < n) lscan[i] = sm[tid];
  if (tid == 255) partials[blockIdx.x] = sm[255];
}

__global__ void k_scan_b(int* __restrict__ partials, int nb) {   // nb <= 1024
  __shared__ int sm[1024];
  int tid = threadIdx.x;
  int v = (tid < nb) ? partials[tid] : 0;
  sm[tid] = v;
  __syncthreads();
  for (int off = 1; off < 1024; off <<= 1) {
    int t = (tid >= off) ? sm[tid - off] : 0;
    __syncthreads();
    sm[tid] += t;
    __syncthreads();
  }
  if (tid < nb) partials[tid] = sm[tid] - v;   // exclusive
}

__global__ void k_scan_c(const int* __restrict__ lscan, const int* __restrict__ vals,
                         const int* __restrict__ partials, int* __restrict__ scanned,
                         int n) {
  int i = blockIdx.x * 256 + threadIdx.x;
  if (i >= n) return;
  scanned[i] = lscan[i] - vals[i] + partials[blockIdx.x];
}

__global__ void b_bptr(const int* __restrict__ scanned, int* __restrict__ bucketPtr,
                       int NBKT, int NBLKE, int E) {
  int i = blockIdx.x * 256 + threadIdx.x;
  if (i < NBKT) bucketPtr[i] = scanned[i * NBLKE];
  if (i == 0) bucketPtr[NBKT] = E;
}

// scatter (dst,src) into bucket regions; LDS cursors only.
__global__ __launch_bounds__(256) void b_scatter(const void* __restrict__ ei,
                                                 const int* __restrict__ flag, int E,
                                                 const int* __restrict__ scanned,
                                                 uint2* __restrict__ ebuf,
                                                 int NBKT, int NBLKE) {
  __shared__ int base[512];
  int blk = blockIdx.x, tid = threadIdx.x;
  for (int i = tid; i < NBKT; i += 256) base[i] = scanned[i * NBLKE + blk];
  __syncthreads();
  int is64 = flag[0];
  int b0 = blk * EPB;
  int cnt = min(EPB, E - b0);
  for (int i = tid; i < cnt; i += 256) {
    int d = edge_at(ei, is64, (long long)E + b0 + i);
    int s = edge_at(ei, is64, b0 + i);
    int pos = atomicAdd(&base[d >> 8], 1);
    ebuf[pos] = make_uint2((unsigned)d, (unsigned)s);
  }
}

// per-bucket counting sort (256 local nodes) -> rowptr + colsrc
__global__ __launch_bounds__(256) void b_pass2(const uint2* __restrict__ ebuf,
                                               const int* __restrict__ bucketPtr,
                                               int* __restrict__ rowptr,
                                               int* __restrict__ colsrc,
                                               int N, int NBKT, int E) {
  __shared__ int hist[256], excl[256], cur[256], sm[256];
  int b = blockIdx.x, tid = threadIdx.x;
  hist[tid] = 0;
  __syncthreads();
  int beg = bucketPtr[b], end = bucketPtr[b + 1];
  for (int i = beg + tid; i < end; i += 256)
    atomicAdd(&hist[ebuf[i].x & 255], 1);
  __syncthreads();
  int v = hist[tid];
  sm[tid] = v;
  __syncthreads();
  for (int off = 1; off < 256; off <<= 1) {
    int t = (tid >= off) ? sm[tid - off] : 0;
    __syncthreads();
    sm[tid] += t;
    __syncthreads();
  }
  excl[tid] = sm[tid] - v;
  cur[tid] = 0;
  __syncthreads();
  int nb0 = b << 8;
  if (nb0 + tid < N) rowptr[nb0 + tid] = beg + excl[tid];
  if (b == 0 && tid == 0) rowptr[N] = E;
  for (int i = beg + tid; i < end; i += 256) {
    uint2 e2 = ebuf[i];
    int dl = (int)(e2.x & 255u);
    int r = atomicAdd(&cur[dl], 1);
    colsrc[beg + excl[dl] + r] = (int)e2.y;
  }
}

// --------------------------- aggregation ------------------------------------
// 128-wide bf16 agg: 1 wave/node, 16 lanes x 8 feats, 4 edges concurrent,
// 2-deep pipeline, shfl-xor reduce across edge-subgroups.
__global__ void k_agg128b(const unsigned int* __restrict__ H,
                          const int* __restrict__ rowptr, const int* __restrict__ colsrc,
                          unsigned int* __restrict__ out, int N) {
  int node = blockIdx.x * 4 + (threadIdx.x >> 6);
  if (node >= N) return;
  int l = threadIdx.x & 63;
  int sub = l >> 4, fl = l & 15;
  int beg = rowptr[node], end = rowptr[node + 1];
  float a[8] = {0.f, 0.f, 0.f, 0.f, 0.f, 0.f, 0.f, 0.f};
  int i = beg + sub;
  for (; i + 4 < end; i += 8) {
    int s0 = colsrc[i], s1 = colsrc[i + 4];
    uint4 v0 = *reinterpret_cast<const uint4*>(H + (size_t)s0 * 64 + fl * 4);
    uint4 v1 = *reinterpret_cast<const uint4*>(H + (size_t)s1 * 64 + fl * 4);
    a[0] += bflo(v0.x) + bflo(v1.x); a[1] += bfhi(v0.x) + bfhi(v1.x);
    a[2] += bflo(v0.y) + bflo(v1.y); a[3] += bfhi(v0.y) + bfhi(v1.y);
    a[4] += bflo(v0.z) + bflo(v1.z); a[5] += bfhi(v0.z) + bfhi(v1.z);
    a[6] += bflo(v0.w) + bflo(v1.w); a[7] += bfhi(v0.w) + bfhi(v1.w);
  }
  if (i < end) {
    uint4 v = *reinterpret_cast<const uint4*>(H + (size_t)colsrc[i] * 64 + fl * 4);
    a[0] += bflo(v.x); a[1] += bfhi(v.x);
    a[2] += bflo(v.y); a[3] += bfhi(v.y);
    a[4] += bflo(v.z); a[5] += bfhi(v.z);
    a[6] += bflo(v.w); a[7] += bfhi(v.w);
  }
  #pragma unroll
  for (int k = 0; k < 8; ++k) {
    a[k] += __shfl_xor(a[k], 16);
    a[k] += __shfl_xor(a[k], 32);
  }
  if (sub == 0) {
    uint4 o;
    o.x = ((unsigned)f2bf(a[1]) << 16) | f2bf(a[0]);
    o.y = ((unsigned)f2bf(a[3]) << 16) | f2bf(a[2]);
    o.z = ((unsigned)f2bf(a[5]) << 16) | f2bf(a[4]);
    o.w = ((unsigned)f2bf(a[7]) << 16) | f2bf(a[6]);
    *reinterpret_cast<uint4*>(out + (size_t)node * 64 + fl * 4) = o;
  }
}

// 40-wide final agg from padded [N][48] bf16; out f32 [N][40] + b2.
// 12 active lanes x 4 feats (uint2), 4 edges concurrent.
__global__ void k_agg40(const unsigned int* __restrict__ T,
                        const int* __restrict__ rowptr, const int* __restrict__ colsrc,
                        const float* __restrict__ b2, float* __restrict__ out, int N) {
  int node = blockIdx.x * 4 + (threadIdx.x >> 6);
  if (node >= N) return;
  int l = threadIdx.x & 63;
  int sub = l >> 4, fl = l & 15;
  int beg = rowptr[node], end = rowptr[node + 1];
  float a[4] = {0.f, 0.f, 0.f, 0.f};
  if (fl < 12) {
    int i = beg + sub;
    for (; i + 4 < end; i += 8) {
      int s0 = colsrc[i], s1 = colsrc[i + 4];
      uint2 v0 = *reinterpret_cast<const uint2*>(T + (size_t)s0 * 24 + fl * 2);
      uint2 v1 = *reinterpret_cast<const uint2*>(T + (size_t)s1 * 24 + fl * 2);
      a[0] += bflo(v0.x) + bflo(v1.x); a[1] += bfhi(v0.x) + bfhi(v1.x);
      a[2] += bflo(v0.y) + bflo(v1.y); a[3] += bfhi(v0.y) + bfhi(v1.y);
    }
    if (i < end) {
      uint2 v = *reinterpret_cast<const uint2*>(T + (size_t)colsrc[i] * 24 + fl * 2);
      a[0] += bflo(v.x); a[1] += bfhi(v.x);
      a[2] += bflo(v.y); a[3] += bfhi(v.y);
    }
  }
  #pragma unroll
  for (int k = 0; k < 4; ++k) {
    a[k] += __shfl_xor(a[k], 16);
    a[k] += __shfl_xor(a[k], 32);
  }
  if (sub == 0 && fl < 10) {
    float4 o;
    o.x = a[0] + b2[fl * 4 + 0];
    o.y = a[1] + b2[fl * 4 + 1];
    o.z = a[2] + b2[fl * 4 + 2];
    o.w = a[3] + b2[fl * 4 + 3];
    *reinterpret_cast<float4*>(out + (size_t)node * 40 + fl * 4) = o;
  }
}

// --------------------------- GEMM (MFMA bf16) -------------------------------
// C[N][Fp] = act(A[N][128] @ W + bias) in bf16. Wt is [Fp][128] bf16.
__global__ __launch_bounds__(256) void k_gemm(const unsigned short* __restrict__ A,
                                              const unsigned short* __restrict__ Wt,
                                              const float* __restrict__ bias,
                                              unsigned short* __restrict__ C,
                                              int N, int Fp, int relu) {
  int tid = threadIdx.x;
  int w = tid >> 6, l = tid & 63;
  int r0 = blockIdx.x * 64 + w * 16;
  int arow = r0 + (l & 15);
  if (arow >= N) arow = N - 1;
  int kk = (l >> 4) * 8;
  bf16x8 a[4];
  #pragma unroll
  for (int ks = 0; ks < 4; ++ks)
    a[ks] = *reinterpret_cast<const bf16x8*>(A + (size_t)arow * 128 + ks * 32 + kk);

  int crow0 = r0 + (l >> 4) * 4;
  int ccol = l & 15;
  for (int cf = 0; cf < Fp / 16; ++cf) {
    f32x4 acc = {0.f, 0.f, 0.f, 0.f};
    const unsigned short* wp = Wt + (size_t)(cf * 16 + ccol) * 128 + kk;
    #pragma unroll
    for (int ks = 0; ks < 4; ++ks) {
      bf16x8 b = *reinterpret_cast<const bf16x8*>(wp + ks * 32);
      acc = __builtin_amdgcn_mfma_f32_16x16x32_bf16(a[ks], b, acc, 0, 0, 0);
    }
    float bv = bias ? bias[cf * 16 + ccol] : 0.f;
    #pragma unroll
    for (int r = 0; r < 4; ++r) {
      int gr = crow0 + r;
      if (gr >= N) continue;
      float v = acc[r] + bv;
      if (relu) v = fmaxf(v, 0.f);
      C[(size_t)gr * Fp + cf * 16 + ccol] = f2bf(v);
    }
  }
}

extern "C" void kernel_launch(void* const* d_in, const int* in_sizes, int n_in,
                              void* d_out, int out_size, void* d_ws, size_t ws_size,
                              hipStream_t stream) {
  const float* x  = (const float*)d_in[0];
  const void*  ei = d_in[1];
  const float* W0 = (const float*)d_in[2];
  const float* b0 = (const float*)d_in[3];
  const float* W1 = (const float*)d_in[4];
  const float* b1 = (const float*)d_in[5];
  const float* W2 = (const float*)d_in[6];
  const float* b2 = (const float*)d_in[7];
  float* out = (float*)d_out;

  const int N = in_sizes[0] / 128;     // 100000
  const int E = in_sizes[1] / 2;       // 1600000
  const int FOUT = in_sizes[6] / 128;  // 40
  const int FP3 = 48;

  const int NBLKE = (E + EPB - 1) / EPB;        // 391
  const int NBKT  = (N + 255) / 256;            // 391
  const int T     = NBKT * NBLKE;               // 152,881
  const int GS    = (T + 255) / 256;            // 598 (<=1024)

  char* wp = (char*)d_ws;
  auto alloc = [&](size_t bytes) -> void* {
    void* p = (void*)wp;
    wp += (bytes + 255) & ~(size_t)255;
    return p;
  };
  unsigned short* xb   = (unsigned short*)alloc((size_t)N * 128 * 2);
  unsigned short* bufA = (unsigned short*)alloc((size_t)N * 128 * 2);
  unsigned short* bufH = (unsigned short*)alloc((size_t)N * 128 * 2);
  unsigned short* t3   = (unsigned short*)alloc((size_t)N * FP3 * 2);
  unsigned short* Wt0  = (unsigned short*)alloc(128 * 128 * 2);
  unsigned short* Wt1  = (unsigned short*)alloc(128 * 128 * 2);
  unsigned short* Wt2  = (unsigned short*)alloc(FP3 * 128 * 2);
  uint2* ebuf   = (uint2*)alloc((size_t)E * 8);
  int* colsrc   = (int*)alloc((size_t)E * 4);
  int* rowptr   = (int*)alloc((size_t)(N + 1) * 4);
  int* bhist    = (int*)alloc((size_t)T * 4);
  int* lscan    = (int*)alloc((size_t)T * 4);
  int* scanned  = (int*)alloc((size_t)T * 4);
  int* partials = (int*)alloc(4096);
  int* bucketPtr= (int*)alloc((size_t)(NBKT + 1) * 4);
  int* flag     = (int*)alloc(256);

  k_detect<<<1, 64, 0, stream>>>((const int*)ei, flag);
  long long n4 = (long long)N * 32;
  k_cvt<<<(int)((n4 + 255) / 256), 256, 0, stream>>>(x, xb, n4);
  k_wt<<<(128 * 128 + 255) / 256, 256, 0, stream>>>(W0, Wt0, 128, 128);
  k_wt<<<(128 * 128 + 255) / 256, 256, 0, stream>>>(W1, Wt1, 128, 128);
  k_wt<<<(FP3 * 128 + 255) / 256, 256, 0, stream>>>(W2, Wt2, FOUT, FP3);

  // CSR build
  b_hist<<<NBLKE, 256, 0, stream>>>(ei, flag, E, bhist, NBKT, NBLKE);
  k_scan_a<<<GS, 256, 0, stream>>>(bhist, lscan, partials, T);
  k_scan_b<<<1, 1024, 0, stream>>>(partials, GS);
  k_scan_c<<<GS, 256, 0, stream>>>(lscan, bhist, partials, scanned, T);
  b_bptr<<<(NBKT + 256) / 256, 256, 0, stream>>>(scanned, bucketPtr, NBKT, NBLKE, E);
  b_scatter<<<NBLKE, 256, 0, stream>>>(ei, flag, E, scanned, ebuf, NBKT, NBLKE);
  b_pass2<<<NBKT, 256, 0, stream>>>(ebuf, bucketPtr, rowptr, colsrc, N, NBKT, E);

  int gagg = (N + 3) / 4;
  int ggemm = (N + 63) / 64;
  // layer 1
  k_agg128b<<<gagg, 256, 0, stream>>>((const unsigned int*)xb, rowptr, colsrc,
                                      (unsigned int*)bufA, N);
  k_gemm<<<ggemm, 256, 0, stream>>>(bufA, Wt0, b0, bufH, N, 128, 1);
  // layer 2
  k_agg128b<<<gagg, 256, 0, stream>>>((const unsigned int*)bufH, rowptr, colsrc,
                                      (unsigned int*)bufA, N);
  k_gemm<<<ggemm, 256, 0, stream>>>(bufA, Wt1, b1, bufH, N, 128, 1);
  // layer 3
  k_gemm<<<ggemm, 256, 0, stream>>>(bufH, Wt2, nullptr, t3, N, FP3, 0);
  k_agg40<<<gagg, 256, 0, stream>>>((const unsigned int*)t3, rowptr, colsrc, b2, out, N);
}

// Round 4
// 317.222 us; speedup vs baseline: 2.1857x; 1.0143x over previous
//
#include <hip/hip_runtime.h>

// ---------------------------------------------------------------------------
// GCN: out = agg(relu(agg(relu(agg(x)W0+b0))W1+b1) @ W2) + b2
// R4: fused agg+MFMA-GEMM per layer (wave-private LDS tile, XOR-swizzled);
//     layer2 chains @W2 in-kernel; 16-deep gather ILP; 12 dispatches.
// ---------------------------------------------------------------------------

typedef short bf16x8 __attribute__((ext_vector_type(8)));
typedef float f32x4  __attribute__((ext_vector_type(4)));

#define EPB 4096   // edges per routing block

__device__ __forceinline__ float bflo(unsigned int v) {
  union { float f; unsigned int i; } w; w.i = v << 16; return w.f;
}
__device__ __forceinline__ float bfhi(unsigned int v) {
  union { float f; unsigned int i; } w; w.i = v & 0xffff0000u; return w.f;
}
__device__ __forceinline__ unsigned short f2bf(float f) {
  union { float f; unsigned int i; } w; w.f = f;
  unsigned int b = w.i;
  unsigned int r = (b + 0x7fffu + ((b >> 16) & 1u)) >> 16;   // RNE
  return (unsigned short)r;
}

__device__ __forceinline__ int edge_at(const void* ei, int is64, long long pos) {
  if (is64) return (int)((const long long*)ei)[pos];
  return ((const int*)ei)[pos];
}

__global__ void k_detect(const int* __restrict__ ei32, int* __restrict__ flag) {
  int tid = threadIdx.x;
  int v = ei32[2 * tid + 1];
  unsigned long long m = __ballot(v != 0);
  if (tid == 0) flag[0] = (m == 0ull) ? 1 : 0;
}

__global__ void k_cvt(const float* __restrict__ in, unsigned short* __restrict__ out,
                      long long n4) {
  long long i = (long long)blockIdx.x * blockDim.x + threadIdx.x;
  if (i >= n4) return;
  float4 v = *reinterpret_cast<const float4*>(in + i * 4);
  ushort4 o;
  o.x = f2bf(v.x); o.y = f2bf(v.y); o.z = f2bf(v.z); o.w = f2bf(v.w);
  *reinterpret_cast<ushort4*>(out + i * 4) = o;
}

// all three transposed weights in one launch
__global__ void k_wt3(const float* __restrict__ W0, const float* __restrict__ W1,
                      const float* __restrict__ W2,
                      unsigned short* __restrict__ Wt0, unsigned short* __restrict__ Wt1,
                      unsigned short* __restrict__ Wt2, int FOUT, int FP3) {
  int idx = blockIdx.x * blockDim.x + threadIdx.x;
  if (idx < 16384) {
    int c = idx >> 7, k = idx & 127;
    Wt0[c * 128 + k] = f2bf(W0[k * 128 + c]);
  } else if (idx < 32768) {
    int t = idx - 16384;
    int c = t >> 7, k = t & 127;
    Wt1[c * 128 + k] = f2bf(W1[k * 128 + c]);
  } else {
    int t = idx - 32768;
    if (t < FP3 * 128) {
      int c = t >> 7, k = t & 127;
      Wt2[c * 128 + k] = (c < FOUT) ? f2bf(W2[k * FOUT + c]) : (unsigned short)0;
    }
  }
}

// --------------------------- CSR build --------------------------------------
__global__ __launch_bounds__(256) void b_hist(const void* __restrict__ ei,
                                              const int* __restrict__ flag, int E,
                                              int* __restrict__ bhist,
                                              int NBKT, int NBLKE) {
  __shared__ int h[512];
  int blk = blockIdx.x, tid = threadIdx.x;
  for (int i = tid; i < NBKT; i += 256) h[i] = 0;
  __syncthreads();
  int is64 = flag[0];
  int base = blk * EPB;
  int cnt = min(EPB, E - base);
  for (int i = tid; i < cnt; i += 256) {
    int d = edge_at(ei, is64, (long long)E + base + i);
    atomicAdd(&h[d >> 8], 1);
  }
  __syncthreads();
  for (int i = tid; i < NBKT; i += 256) bhist[i * NBLKE + blk] = h[i];
}

__global__ void k_scan_a(const int* __restrict__ vals, int* __restrict__ lscan,
                         int* __restrict__ partials, int n) {
  __shared__ int sm[256];
  int tid = threadIdx.x;
  int i = blockIdx.x * 256 + tid;
  int v = (i < n) ? vals[i] : 0;
  sm[tid] = v;
  __syncthreads();
  for (int off = 1; off < 256; off <<= 1) {
    int t = (tid >= off) ? sm[tid - off] : 0;
    __syncthreads();
    sm[tid] += t;
    __syncthreads();
  }
  if (i < n) lscan[i] = sm[tid];
  if (tid == 255) partials[blockIdx.x] = sm[255];
}

__global__ void k_scan_b(int* __restrict__ partials, int nb) {   // nb <= 1024
  __shared__ int sm[1024];
  int tid = threadIdx.x;
  int v = (tid < nb) ? partials[tid] : 0;
  sm[tid] = v;
  __syncthreads();
  for (int off = 1; off < 1024; off <<= 1) {
    int t = (tid >= off) ? sm[tid - off] : 0;
    __syncthreads();
    sm[tid] += t;
    __syncthreads();
  }
  if (tid < nb) partials[tid] = sm[tid] - v;   // exclusive
}

// exclusive scan writeback + bucketPtr extraction (merged b_bptr)
__global__ void k_scan_c(const int* __restrict__ lscan, const int* __restrict__ vals,
                         const int* __restrict__ partials, int* __restrict__ scanned,
                         int* __restrict__ bucketPtr, int n, int NBLKE, int NBKT, int E) {
  int i = blockIdx.x * 256 + threadIdx.x;
  if (i >= n) return;
  int v = lscan[i] - vals[i] + partials[blockIdx.x];
  scanned[i] = v;
  int q = i / NBLKE;
  if (i - q * NBLKE == 0) bucketPtr[q] = v;
  if (i == 0) bucketPtr[NBKT] = E;
}

__global__ __launch_bounds__(256) void b_scatter(const void* __restrict__ ei,
                                                 const int* __restrict__ flag, int E,
                                                 const int* __restrict__ scanned,
                                                 uint2* __restrict__ ebuf,
                                                 int NBKT, int NBLKE) {
  __shared__ int base[512];
  int blk = blockIdx.x, tid = threadIdx.x;
  for (int i = tid; i < NBKT; i += 256) base[i] = scanned[i * NBLKE + blk];
  __syncthreads();
  int is64 = flag[0];
  int b0 = blk * EPB;
  int cnt = min(EPB, E - b0);
  for (int i = tid; i < cnt; i += 256) {
    int d = edge_at(ei, is64, (long long)E + b0 + i);
    int s = edge_at(ei, is64, b0 + i);
    int pos = atomicAdd(&base[d >> 8], 1);
    ebuf[pos] = make_uint2((unsigned)d, (unsigned)s);
  }
}

__global__ __launch_bounds__(256) void b_pass2(const uint2* __restrict__ ebuf,
                                               const int* __restrict__ bucketPtr,
                                               int* __restrict__ rowptr,
                                               int* __restrict__ colsrc,
                                               int N, int NBKT, int E) {
  __shared__ int hist[256], excl[256], cur[256], sm[256];
  int b = blockIdx.x, tid = threadIdx.x;
  hist[tid] = 0;
  __syncthreads();
  int beg = bucketPtr[b], end = bucketPtr[b + 1];
  for (int i = beg + tid; i < end; i += 256)
    atomicAdd(&hist[ebuf[i].x & 255], 1);
  __syncthreads();
  int v = hist[tid];
  sm[tid] = v;
  __syncthreads();
  for (int off = 1; off < 256; off <<= 1) {
    int t = (tid >= off) ? sm[tid - off] : 0;
    __syncthreads();
    sm[tid] += t;
    __syncthreads();
  }
  excl[tid] = sm[tid] - v;
  cur[tid] = 0;
  __syncthreads();
  int nb0 = b << 8;
  if (nb0 + tid < N) rowptr[nb0 + tid] = beg + excl[tid];
  if (b == 0 && tid == 0) rowptr[N] = E;
  for (int i = beg + tid; i < end; i += 256) {
    uint2 e2 = ebuf[i];
    int dl = (int)(e2.x & 255u);
    int r = atomicAdd(&cur[dl], 1);
    colsrc[beg + excl[dl] + r] = (int)e2.y;
  }
}

// ------------------------ fused agg + GEMM ----------------------------------
// Wave aggregates 16 nodes into a wave-private LDS tile (bf16, XOR-swizzled
// 16B chunks), reads MFMA A-fragments back, multiplies by Wt (+bias, relu).
// MODE 0: write C (128 cols) to global bf16.
// MODE 1: chain: C2 (relu(.@W1+b1)) staged to LDS, then @Wt2 -> t3 (FP3 cols).
template <int MODE>
__global__ __launch_bounds__(256) void k_fuse(const unsigned int* __restrict__ H,
                                              const int* __restrict__ rowptr,
                                              const int* __restrict__ colsrc,
                                              const unsigned short* __restrict__ Wt,
                                              const float* __restrict__ bias,
                                              const unsigned short* __restrict__ Wt2,
                                              unsigned short* __restrict__ C,
                                              int N, int FP3) {
  __shared__ unsigned int sh[4096];            // 16 KB: 4 waves x 16 nodes x 256B
  int tid = threadIdx.x;
  int w = tid >> 6, l = tid & 63;
  int sub = l >> 4, fl = l & 15;
  int tile = blockIdx.x * 64 + w * 16;
  unsigned int* my = &sh[w * 1024];

  // ---- phase A: aggregate 16 nodes -> LDS bf16 tile ----
  for (int j = 0; j < 16; ++j) {
    int node = tile + j;
    float a[8] = {0.f, 0.f, 0.f, 0.f, 0.f, 0.f, 0.f, 0.f};
    if (node < N) {
      int beg = rowptr[node], end = rowptr[node + 1];
      int i = beg + sub;
      for (; i + 12 < end; i += 16) {
        int s0 = colsrc[i], s1 = colsrc[i + 4], s2 = colsrc[i + 8], s3 = colsrc[i + 12];
        uint4 v0 = *reinterpret_cast<const uint4*>(H + (size_t)s0 * 64 + fl * 4);
        uint4 v1 = *reinterpret_cast<const uint4*>(H + (size_t)s1 * 64 + fl * 4);
        uint4 v2 = *reinterpret_cast<const uint4*>(H + (size_t)s2 * 64 + fl * 4);
        uint4 v3 = *reinterpret_cast<const uint4*>(H + (size_t)s3 * 64 + fl * 4);
        a[0] += (bflo(v0.x) + bflo(v1.x)) + (bflo(v2.x) + bflo(v3.x));
        a[1] += (bfhi(v0.x) + bfhi(v1.x)) + (bfhi(v2.x) + bfhi(v3.x));
        a[2] += (bflo(v0.y) + bflo(v1.y)) + (bflo(v2.y) + bflo(v3.y));
        a[3] += (bfhi(v0.y) + bfhi(v1.y)) + (bfhi(v2.y) + bfhi(v3.y));
        a[4] += (bflo(v0.z) + bflo(v1.z)) + (bflo(v2.z) + bflo(v3.z));
        a[5] += (bfhi(v0.z) + bfhi(v1.z)) + (bfhi(v2.z) + bfhi(v3.z));
        a[6] += (bflo(v0.w) + bflo(v1.w)) + (bflo(v2.w) + bflo(v3.w));
        a[7] += (bfhi(v0.w) + bfhi(v1.w)) + (bfhi(v2.w) + bfhi(v3.w));
      }
      for (; i < end; i += 4) {
        uint4 v = *reinterpret_cast<const uint4*>(H + (size_t)colsrc[i] * 64 + fl * 4);
        a[0] += bflo(v.x); a[1] += bfhi(v.x);
        a[2] += bflo(v.y); a[3] += bfhi(v.y);
        a[4] += bflo(v.z); a[5] += bfhi(v.z);
        a[6] += bflo(v.w); a[7] += bfhi(v.w);
      }
    }
    #pragma unroll
    for (int k = 0; k < 8; ++k) {
      a[k] += __shfl_xor(a[k], 16);
      a[k] += __shfl_xor(a[k], 32);
    }
    if (sub == 0) {
      uint4 o;
      o.x = ((unsigned)f2bf(a[1]) << 16) | f2bf(a[0]);
      o.y = ((unsigned)f2bf(a[3]) << 16) | f2bf(a[2]);
      o.z = ((unsigned)f2bf(a[5]) << 16) | f2bf(a[4]);
      o.w = ((unsigned)f2bf(a[7]) << 16) | f2bf(a[6]);
      *reinterpret_cast<uint4*>(&my[j * 64 + ((fl ^ j) << 2)]) = o;   // swizzled chunk
    }
  }

  // ---- phase B: A fragments from LDS, MFMA vs Wt ----
  int n = fl;                                   // A row within tile
  bf16x8 af[4];
  #pragma unroll
  for (int ks = 0; ks < 4; ++ks) {
    int c = (ks << 2) | sub;
    af[ks] = *reinterpret_cast<const bf16x8*>(&my[n * 64 + ((c ^ n) << 2)]);
  }
  int kk = sub * 8;
  int ccol = fl;

  if (MODE == 0) {
    #pragma unroll
    for (int cf = 0; cf < 8; ++cf) {
      f32x4 acc = {0.f, 0.f, 0.f, 0.f};
      const unsigned short* wp = Wt + (size_t)(cf * 16 + ccol) * 128 + kk;
      #pragma unroll
      for (int ks = 0; ks < 4; ++ks) {
        bf16x8 b = *reinterpret_cast<const bf16x8*>(wp + ks * 32);
        acc = __builtin_amdgcn_mfma_f32_16x16x32_bf16(af[ks], b, acc, 0, 0, 0);
      }
      float bv = bias[cf * 16 + ccol];
      #pragma unroll
      for (int r = 0; r < 4; ++r) {
        int gr = tile + sub * 4 + r;
        if (gr < N) {
          float v = fmaxf(acc[r] + bv, 0.f);
          C[(size_t)gr * 128 + cf * 16 + ccol] = f2bf(v);
        }
      }
    }
  } else {
    // C2 = relu(A@Wt + bias) staged to LDS bf16 (swizzled), then @Wt2 -> t3
    unsigned short* sh16 = (unsigned short*)my;   // 16x128 bf16 region (4 KB)
    #pragma unroll
    for (int cf = 0; cf < 8; ++cf) {
      f32x4 acc = {0.f, 0.f, 0.f, 0.f};
      const unsigned short* wp = Wt + (size_t)(cf * 16 + ccol) * 128 + kk;
      #pragma unroll
      for (int ks = 0; ks < 4; ++ks) {
        bf16x8 b = *reinterpret_cast<const bf16x8*>(wp + ks * 32);
        acc = __builtin_amdgcn_mfma_f32_16x16x32_bf16(af[ks], b, acc, 0, 0, 0);
      }
      float bv = bias[cf * 16 + ccol];
      int col = cf * 16 + ccol;
      int chunk = col >> 3;
      #pragma unroll
      for (int r = 0; r < 4; ++r) {
        int row = sub * 4 + r;
        float v = fmaxf(acc[r] + bv, 0.f);
        sh16[row * 128 + ((chunk ^ row) << 3) + (col & 7)] = f2bf(v);
      }
    }
    // A3 fragments (h2 tile) from LDS
    bf16x8 af3[4];
    #pragma unroll
    for (int ks = 0; ks < 4; ++ks) {
      int c = (ks << 2) | sub;
      af3[ks] = *reinterpret_cast<const bf16x8*>(&sh16[n * 128 + ((c ^ n) << 3)]);
    }
    for (int cf = 0; cf < FP3 / 16; ++cf) {
      f32x4 acc = {0.f, 0.f, 0.f, 0.f};
      const unsigned short* wp = Wt2 + (size_t)(cf * 16 + ccol) * 128 + kk;
      #pragma unroll
      for (int ks = 0; ks < 4; ++ks) {
        bf16x8 b = *reinterpret_cast<const bf16x8*>(wp + ks * 32);
        acc = __builtin_amdgcn_mfma_f32_16x16x32_bf16(af3[ks], b, acc, 0, 0, 0);
      }
      #pragma unroll
      for (int r = 0; r < 4; ++r) {
        int gr = tile + sub * 4 + r;
        if (gr < N)
          C[(size_t)gr * FP3 + cf * 16 + ccol] = f2bf(acc[r]);
      }
    }
  }
}

// 40-wide final agg from padded [N][FP3] bf16; out f32 [N][40] + b2.
__global__ void k_agg40(const unsigned int* __restrict__ T,
                        const int* __restrict__ rowptr, const int* __restrict__ colsrc,
                        const float* __restrict__ b2, float* __restrict__ out, int N) {
  int node = blockIdx.x * 4 + (threadIdx.x >> 6);
  if (node >= N) return;
  int l = threadIdx.x & 63;
  int sub = l >> 4, fl = l & 15;
  int beg = rowptr[node], end = rowptr[node + 1];
  float a[4] = {0.f, 0.f, 0.f, 0.f};
  if (fl < 12) {
    int i = beg + sub;
    for (; i + 12 < end; i += 16) {
      int s0 = colsrc[i], s1 = colsrc[i + 4], s2 = colsrc[i + 8], s3 = colsrc[i + 12];
      uint2 v0 = *reinterpret_cast<const uint2*>(T + (size_t)s0 * 24 + fl * 2);
      uint2 v1 = *reinterpret_cast<const uint2*>(T + (size_t)s1 * 24 + fl * 2);
      uint2 v2 = *reinterpret_cast<const uint2*>(T + (size_t)s2 * 24 + fl * 2);
      uint2 v3 = *reinterpret_cast<const uint2*>(T + (size_t)s3 * 24 + fl * 2);
      a[0] += (bflo(v0.x) + bflo(v1.x)) + (bflo(v2.x) + bflo(v3.x));
      a[1] += (bfhi(v0.x) + bfhi(v1.x)) + (bfhi(v2.x) + bfhi(v3.x));
      a[2] += (bflo(v0.y) + bflo(v1.y)) + (bflo(v2.y) + bflo(v3.y));
      a[3] += (bfhi(v0.y) + bfhi(v1.y)) + (bfhi(v2.y) + bfhi(v3.y));
    }
    for (; i < end; i += 4) {
      uint2 v = *reinterpret_cast<const uint2*>(T + (size_t)colsrc[i] * 24 + fl * 2);
      a[0] += bflo(v.x); a[1] += bfhi(v.x);
      a[2] += bflo(v.y); a[3] += bfhi(v.y);
    }
  }
  #pragma unroll
  for (int k = 0; k < 4; ++k) {
    a[k] += __shfl_xor(a[k], 16);
    a[k] += __shfl_xor(a[k], 32);
  }
  if (sub == 0 && fl < 10) {
    float4 o;
    o.x = a[0] + b2[fl * 4 + 0];
    o.y = a[1] + b2[fl * 4 + 1];
    o.z = a[2] + b2[fl * 4 + 2];
    o.w = a[3] + b2[fl * 4 + 3];
    *reinterpret_cast<float4*>(out + (size_t)node * 40 + fl * 4) = o;
  }
}

extern "C" void kernel_launch(void* const* d_in, const int* in_sizes, int n_in,
                              void* d_out, int out_size, void* d_ws, size_t ws_size,
                              hipStream_t stream) {
  const float* x  = (const float*)d_in[0];
  const void*  ei = d_in[1];
  const float* W0 = (const float*)d_in[2];
  const float* b0 = (const float*)d_in[3];
  const float* W1 = (const float*)d_in[4];
  const float* b1 = (const float*)d_in[5];
  const float* W2 = (const float*)d_in[6];
  const float* b2 = (const float*)d_in[7];
  float* out = (float*)d_out;

  const int N = in_sizes[0] / 128;     // 100000
  const int E = in_sizes[1] / 2;       // 1600000
  const int FOUT = in_sizes[6] / 128;  // 40
  const int FP3 = 48;

  const int NBLKE = (E + EPB - 1) / EPB;        // 391
  const int NBKT  = (N + 255) / 256;            // 391
  const int T     = NBKT * NBLKE;               // 152,881
  const int GS    = (T + 255) / 256;            // 598 (<=1024)

  char* wp = (char*)d_ws;
  auto alloc = [&](size_t bytes) -> void* {
    void* p = (void*)wp;
    wp += (bytes + 255) & ~(size_t)255;
    return p;
  };
  unsigned short* xb   = (unsigned short*)alloc((size_t)N * 128 * 2);
  unsigned short* bufH = (unsigned short*)alloc((size_t)N * 128 * 2);
  unsigned short* t3   = (unsigned short*)alloc((size_t)N * FP3 * 2);
  unsigned short* Wt0  = (unsigned short*)alloc(128 * 128 * 2);
  unsigned short* Wt1  = (unsigned short*)alloc(128 * 128 * 2);
  unsigned short* Wt2  = (unsigned short*)alloc(FP3 * 128 * 2);
  uint2* ebuf   = (uint2*)alloc((size_t)E * 8);
  int* colsrc   = (int*)alloc((size_t)E * 4);
  int* rowptr   = (int*)alloc((size_t)(N + 1) * 4);
  int* bhist    = (int*)alloc((size_t)T * 4);
  int* lscan    = (int*)alloc((size_t)T * 4);
  int* scanned  = (int*)alloc((size_t)T * 4);
  int* partials = (int*)alloc(4096);
  int* bucketPtr= (int*)alloc((size_t)(NBKT + 1) * 4);
  int* flag     = (int*)alloc(256);

  k_detect<<<1, 64, 0, stream>>>((const int*)ei, flag);
  long long n4 = (long long)N * 32;
  k_cvt<<<(int)((n4 + 255) / 256), 256, 0, stream>>>(x, xb, n4);
  k_wt3<<<(32768 + FP3 * 128 + 255) / 256, 256, 0, stream>>>(W0, W1, W2, Wt0, Wt1, Wt2,
                                                             FOUT, FP3);
  // CSR build
  b_hist<<<NBLKE, 256, 0, stream>>>(ei, flag, E, bhist, NBKT, NBLKE);
  k_scan_a<<<GS, 256, 0, stream>>>(bhist, lscan, partials, T);
  k_scan_b<<<1, 1024, 0, stream>>>(partials, GS);
  k_scan_c<<<GS, 256, 0, stream>>>(lscan, bhist, partials, scanned, bucketPtr,
                                   T, NBLKE, NBKT, E);
  b_scatter<<<NBLKE, 256, 0, stream>>>(ei, flag, E, scanned, ebuf, NBKT, NBLKE);
  b_pass2<<<NBKT, 256, 0, stream>>>(ebuf, bucketPtr, rowptr, colsrc, N, NBKT, E);

  int gfuse = (N + 63) / 64;
  // layer 1: h1 = relu(agg(x)@W0+b0)
  k_fuse<0><<<gfuse, 256, 0, stream>>>((const unsigned int*)xb, rowptr, colsrc,
                                       Wt0, b0, nullptr, bufH, N, FP3);
  // layers 2+3a: t3 = relu(agg(h1)@W1+b1) @ W2
  k_fuse<1><<<gfuse, 256, 0, stream>>>((const unsigned int*)bufH, rowptr, colsrc,
                                       Wt1, b1, Wt2, t3, N, FP3);
  // layer 3b: out = agg(t3) + b2
  k_agg40<<<(N + 3) / 4, 256, 0, stream>>>((const unsigned int*)t3, rowptr, colsrc,
                                           b2, out, N);
}

// Round 5
// 305.395 us; speedup vs baseline: 2.2703x; 1.0387x over previous
//
#include <hip/hip_runtime.h>

// ---------------------------------------------------------------------------
// GCN: out = agg(relu(agg(relu(agg(x)W0+b0))W1+b1) @ W2) + b2
// R5: revert fusion (TLP > fusion for latency-bound gathers).
//     Split agg (1 wave/node, 100k waves) + MFMA GEMMs; chain-GEMM for
//     layers 2+3a; mega prep kernel; packed 4B edge buffer; t3 padded to
//     128B rows.
// ---------------------------------------------------------------------------

typedef short bf16x8 __attribute__((ext_vector_type(8)));
typedef float f32x4  __attribute__((ext_vector_type(4)));

#define EPB 8192   // edges per routing block

__device__ __forceinline__ float bflo(unsigned int v) {
  union { float f; unsigned int i; } w; w.i = v << 16; return w.f;
}
__device__ __forceinline__ float bfhi(unsigned int v) {
  union { float f; unsigned int i; } w; w.i = v & 0xffff0000u; return w.f;
}
__device__ __forceinline__ unsigned short f2bf(float f) {
  union { float f; unsigned int i; } w; w.f = f;
  unsigned int b = w.i;
  unsigned int r = (b + 0x7fffu + ((b >> 16) & 1u)) >> 16;   // RNE
  return (unsigned short)r;
}

__device__ __forceinline__ int edge_at(const void* ei, int is64, long long pos) {
  if (is64) return (int)((const long long*)ei)[pos];
  return ((const int*)ei)[pos];
}

// per-block int64 detection (odd int32 slots of first 64 values all zero)
__device__ __forceinline__ int detect64(const void* ei, int* s_is64, int tid) {
  if (tid < 64) {
    int v = ((const int*)ei)[2 * tid + 1];
    unsigned long long m = __ballot(v != 0);
    if (tid == 0) *s_is64 = (m == 0ull) ? 1 : 0;
  }
  __syncthreads();
  return *s_is64;
}

// --------------------------- mega prep --------------------------------------
// blocks [0, NBLKE)            : per-chunk bucket histogram (d >> 8)
// blocks [NBLKE, NBLKE+ncvt)   : x f32 -> bf16
// blocks [NBLKE+ncvt, ...)     : weight transpose+convert (Wt0, Wt1, Wt2 pad)
__global__ __launch_bounds__(256) void k_prep(const void* __restrict__ ei, int E,
                                              int* __restrict__ bhist,
                                              int NBKT, int NBLKE,
                                              const float* __restrict__ x,
                                              unsigned short* __restrict__ xb,
                                              long long n4, int ncvt,
                                              const float* __restrict__ W0,
                                              const float* __restrict__ W1,
                                              const float* __restrict__ W2,
                                              unsigned short* __restrict__ Wt0,
                                              unsigned short* __restrict__ Wt1,
                                              unsigned short* __restrict__ Wt2,
                                              int FOUT) {
  int blk = blockIdx.x, tid = threadIdx.x;
  if (blk < NBLKE) {
    __shared__ int h[512];
    __shared__ int s_is64;
    if (tid < 64) {
      int v = ((const int*)ei)[2 * tid + 1];
      unsigned long long m = __ballot(v != 0);
      if (tid == 0) s_is64 = (m == 0ull) ? 1 : 0;
    }
    for (int i = tid; i < NBKT; i += 256) h[i] = 0;
    __syncthreads();
    int is64 = s_is64;
    int base = blk * EPB;
    int cnt = min(EPB, E - base);
    for (int i = tid; i < cnt; i += 256) {
      int d = edge_at(ei, is64, (long long)E + base + i);
      atomicAdd(&h[d >> 8], 1);
    }
    __syncthreads();
    for (int i = tid; i < NBKT; i += 256) bhist[i * NBLKE + blk] = h[i];
  } else if (blk < NBLKE + ncvt) {
    long long i = (long long)(blk - NBLKE) * 256 + tid;
    if (i < n4) {
      float4 v = *reinterpret_cast<const float4*>(x + i * 4);
      ushort4 o;
      o.x = f2bf(v.x); o.y = f2bf(v.y); o.z = f2bf(v.z); o.w = f2bf(v.w);
      *reinterpret_cast<ushort4*>(xb + i * 4) = o;
    }
  } else {
    int idx = (blk - NBLKE - ncvt) * 256 + tid;
    if (idx < 16384) {
      int c = idx >> 7, k = idx & 127;
      Wt0[c * 128 + k] = f2bf(W0[k * 128 + c]);
    } else if (idx < 32768) {
      int t = idx - 16384;
      int c = t >> 7, k = t & 127;
      Wt1[c * 128 + k] = f2bf(W1[k * 128 + c]);
    } else if (idx < 32768 + 8192) {             // FP3=64 cols
      int t = idx - 32768;
      int c = t >> 7, k = t & 127;
      Wt2[c * 128 + k] = (c < FOUT) ? f2bf(W2[k * FOUT + c]) : (unsigned short)0;
    }
  }
}

// --------------------------- scans ------------------------------------------
__global__ void k_scan_a(const int* __restrict__ vals, int* __restrict__ lscan,
                         int* __restrict__ partials, int n) {
  __shared__ int sm[256];
  int tid = threadIdx.x;
  int i = blockIdx.x * 256 + tid;
  int v = (i < n) ? vals[i] : 0;
  sm[tid] = v;
  __syncthreads();
  for (int off = 1; off < 256; off <<= 1) {
    int t = (tid >= off) ? sm[tid - off] : 0;
    __syncthreads();
    sm[tid] += t;
    __syncthreads();
  }
  if (i < n) lscan[i] = sm[tid];
  if (tid == 255) partials[blockIdx.x] = sm[255];
}

__global__ void k_scan_b(int* __restrict__ partials, int nb) {   // nb <= 1024
  __shared__ int sm[1024];
  int tid = threadIdx.x;
  int v = (tid < nb) ? partials[tid] : 0;
  sm[tid] = v;
  __syncthreads();
  for (int off = 1; off < 1024; off <<= 1) {
    int t = (tid >= off) ? sm[tid - off] : 0;
    __syncthreads();
    sm[tid] += t;
    __syncthreads();
  }
  if (tid < nb) partials[tid] = sm[tid] - v;   // exclusive
}

__global__ void k_scan_c(const int* __restrict__ lscan, const int* __restrict__ vals,
                         const int* __restrict__ partials, int* __restrict__ scanned,
                         int* __restrict__ bucketPtr, int n, int NBLKE, int NBKT, int E) {
  int i = blockIdx.x * 256 + threadIdx.x;
  if (i >= n) return;
  int v = lscan[i] - vals[i] + partials[blockIdx.x];
  scanned[i] = v;
  int q = i / NBLKE;
  if (i - q * NBLKE == 0) bucketPtr[q] = v;
  if (i == 0) bucketPtr[NBKT] = E;
}

// --------------------------- scatter + pass2 --------------------------------
// packed edge record: src | (d&255)<<24   (requires N < 2^24)
__global__ __launch_bounds__(256) void b_scatter(const void* __restrict__ ei, int E,
                                                 const int* __restrict__ scanned,
                                                 unsigned* __restrict__ ebuf,
                                                 int NBKT, int NBLKE) {
  __shared__ int base[512];
  __shared__ int s_is64;
  int blk = blockIdx.x, tid = threadIdx.x;
  if (tid < 64) {
    int v = ((const int*)ei)[2 * tid + 1];
    unsigned long long m = __ballot(v != 0);
    if (tid == 0) s_is64 = (m == 0ull) ? 1 : 0;
  }
  for (int i = tid; i < NBKT; i += 256) base[i] = scanned[i * NBLKE + blk];
  __syncthreads();
  int is64 = s_is64;
  int b0 = blk * EPB;
  int cnt = min(EPB, E - b0);
  for (int i = tid; i < cnt; i += 256) {
    int d = edge_at(ei, is64, (long long)E + b0 + i);
    int s = edge_at(ei, is64, b0 + i);
    int pos = atomicAdd(&base[d >> 8], 1);
    ebuf[pos] = (unsigned)s | ((unsigned)(d & 255) << 24);
  }
}

__global__ __launch_bounds__(256) void b_pass2(const unsigned* __restrict__ ebuf,
                                               const int* __restrict__ bucketPtr,
                                               int* __restrict__ rowptr,
                                               int* __restrict__ colsrc,
                                               int N, int NBKT, int E) {
  __shared__ int hist[256], excl[256], cur[256], sm[256];
  int b = blockIdx.x, tid = threadIdx.x;
  hist[tid] = 0;
  __syncthreads();
  int beg = bucketPtr[b], end = bucketPtr[b + 1];
  for (int i = beg + tid; i < end; i += 256)
    atomicAdd(&hist[ebuf[i] >> 24], 1);
  __syncthreads();
  int v = hist[tid];
  sm[tid] = v;
  __syncthreads();
  for (int off = 1; off < 256; off <<= 1) {
    int t = (tid >= off) ? sm[tid - off] : 0;
    __syncthreads();
    sm[tid] += t;
    __syncthreads();
  }
  excl[tid] = sm[tid] - v;
  cur[tid] = 0;
  __syncthreads();
  int nb0 = b << 8;
  if (nb0 + tid < N) rowptr[nb0 + tid] = beg + excl[tid];
  if (b == 0 && tid == 0) rowptr[N] = E;
  for (int i = beg + tid; i < end; i += 256) {
    unsigned e2 = ebuf[i];
    int dl = (int)(e2 >> 24);
    int r = atomicAdd(&cur[dl], 1);
    colsrc[beg + excl[dl] + r] = (int)(e2 & 0xFFFFFFu);
  }
}

// --------------------------- aggregation ------------------------------------
// 128-wide bf16 agg: 1 wave/node, 16 lanes x 8 feats, 16 edges in flight.
__global__ void k_agg128b(const unsigned int* __restrict__ H,
                          const int* __restrict__ rowptr, const int* __restrict__ colsrc,
                          unsigned int* __restrict__ out, int N) {
  int node = blockIdx.x * 4 + (threadIdx.x >> 6);
  if (node >= N) return;
  int l = threadIdx.x & 63;
  int sub = l >> 4, fl = l & 15;
  int beg = rowptr[node], end = rowptr[node + 1];
  float a[8] = {0.f, 0.f, 0.f, 0.f, 0.f, 0.f, 0.f, 0.f};
  int i = beg + sub;
  for (; i + 12 < end; i += 16) {
    int s0 = colsrc[i], s1 = colsrc[i + 4], s2 = colsrc[i + 8], s3 = colsrc[i + 12];
    uint4 v0 = *reinterpret_cast<const uint4*>(H + (size_t)s0 * 64 + fl * 4);
    uint4 v1 = *reinterpret_cast<const uint4*>(H + (size_t)s1 * 64 + fl * 4);
    uint4 v2 = *reinterpret_cast<const uint4*>(H + (size_t)s2 * 64 + fl * 4);
    uint4 v3 = *reinterpret_cast<const uint4*>(H + (size_t)s3 * 64 + fl * 4);
    a[0] += (bflo(v0.x) + bflo(v1.x)) + (bflo(v2.x) + bflo(v3.x));
    a[1] += (bfhi(v0.x) + bfhi(v1.x)) + (bfhi(v2.x) + bfhi(v3.x));
    a[2] += (bflo(v0.y) + bflo(v1.y)) + (bflo(v2.y) + bflo(v3.y));
    a[3] += (bfhi(v0.y) + bfhi(v1.y)) + (bfhi(v2.y) + bfhi(v3.y));
    a[4] += (bflo(v0.z) + bflo(v1.z)) + (bflo(v2.z) + bflo(v3.z));
    a[5] += (bfhi(v0.z) + bfhi(v1.z)) + (bfhi(v2.z) + bfhi(v3.z));
    a[6] += (bflo(v0.w) + bflo(v1.w)) + (bflo(v2.w) + bflo(v3.w));
    a[7] += (bfhi(v0.w) + bfhi(v1.w)) + (bfhi(v2.w) + bfhi(v3.w));
  }
  for (; i < end; i += 4) {
    uint4 v = *reinterpret_cast<const uint4*>(H + (size_t)colsrc[i] * 64 + fl * 4);
    a[0] += bflo(v.x); a[1] += bfhi(v.x);
    a[2] += bflo(v.y); a[3] += bfhi(v.y);
    a[4] += bflo(v.z); a[5] += bfhi(v.z);
    a[6] += bflo(v.w); a[7] += bfhi(v.w);
  }
  #pragma unroll
  for (int k = 0; k < 8; ++k) {
    a[k] += __shfl_xor(a[k], 16);
    a[k] += __shfl_xor(a[k], 32);
  }
  if (sub == 0) {
    uint4 o;
    o.x = ((unsigned)f2bf(a[1]) << 16) | f2bf(a[0]);
    o.y = ((unsigned)f2bf(a[3]) << 16) | f2bf(a[2]);
    o.z = ((unsigned)f2bf(a[5]) << 16) | f2bf(a[4]);
    o.w = ((unsigned)f2bf(a[7]) << 16) | f2bf(a[6]);
    *reinterpret_cast<uint4*>(out + (size_t)node * 64 + fl * 4) = o;
  }
}

// 40-wide final agg from padded [N][64] bf16 (128B rows); out f32 [N][40] + b2.
__global__ void k_agg40(const unsigned int* __restrict__ T,
                        const int* __restrict__ rowptr, const int* __restrict__ colsrc,
                        const float* __restrict__ b2, float* __restrict__ out, int N) {
  int node = blockIdx.x * 4 + (threadIdx.x >> 6);
  if (node >= N) return;
  int l = threadIdx.x & 63;
  int sub = l >> 4, fl = l & 15;
  int beg = rowptr[node], end = rowptr[node + 1];
  float a[4] = {0.f, 0.f, 0.f, 0.f};
  int i = beg + sub;
  for (; i + 12 < end; i += 16) {
    int s0 = colsrc[i], s1 = colsrc[i + 4], s2 = colsrc[i + 8], s3 = colsrc[i + 12];
    uint2 v0 = *reinterpret_cast<const uint2*>(T + (size_t)s0 * 32 + fl * 2);
    uint2 v1 = *reinterpret_cast<const uint2*>(T + (size_t)s1 * 32 + fl * 2);
    uint2 v2 = *reinterpret_cast<const uint2*>(T + (size_t)s2 * 32 + fl * 2);
    uint2 v3 = *reinterpret_cast<const uint2*>(T + (size_t)s3 * 32 + fl * 2);
    a[0] += (bflo(v0.x) + bflo(v1.x)) + (bflo(v2.x) + bflo(v3.x));
    a[1] += (bfhi(v0.x) + bfhi(v1.x)) + (bfhi(v2.x) + bfhi(v3.x));
    a[2] += (bflo(v0.y) + bflo(v1.y)) + (bflo(v2.y) + bflo(v3.y));
    a[3] += (bfhi(v0.y) + bfhi(v1.y)) + (bfhi(v2.y) + bfhi(v3.y));
  }
  for (; i < end; i += 4) {
    uint2 v = *reinterpret_cast<const uint2*>(T + (size_t)colsrc[i] * 32 + fl * 2);
    a[0] += bflo(v.x); a[1] += bfhi(v.x);
    a[2] += bflo(v.y); a[3] += bfhi(v.y);
  }
  #pragma unroll
  for (int k = 0; k < 4; ++k) {
    a[k] += __shfl_xor(a[k], 16);
    a[k] += __shfl_xor(a[k], 32);
  }
  if (sub == 0 && fl < 10) {
    float4 o;
    o.x = a[0] + b2[fl * 4 + 0];
    o.y = a[1] + b2[fl * 4 + 1];
    o.z = a[2] + b2[fl * 4 + 2];
    o.w = a[3] + b2[fl * 4 + 3];
    *reinterpret_cast<float4*>(out + (size_t)node * 40 + fl * 4) = o;
  }
}

// --------------------------- GEMM (MFMA bf16) -------------------------------
// CHAIN=0: C[N][128] = relu(A@Wt + bias)
// CHAIN=1: C[N][64]  = (relu(A@Wt + bias)) @ Wt2   (C2 staged in wave-LDS)
template <int CHAIN>
__global__ __launch_bounds__(256) void k_gemm(const unsigned short* __restrict__ A,
                                              const unsigned short* __restrict__ Wt,
                                              const float* __restrict__ bias,
                                              const unsigned short* __restrict__ Wt2,
                                              unsigned short* __restrict__ C, int N) {
  __shared__ unsigned short sh16[CHAIN ? 4 * 2048 : 64];   // 16 KB when chaining
  int tid = threadIdx.x;
  int w = tid >> 6, l = tid & 63;
  int sub = l >> 4, fl = l & 15;
  int r0 = blockIdx.x * 64 + w * 16;
  int arow = r0 + fl;
  if (arow >= N) arow = N - 1;
  int kk = sub * 8;
  bf16x8 af[4];
  #pragma unroll
  for (int ks = 0; ks < 4; ++ks)
    af[ks] = *reinterpret_cast<const bf16x8*>(A + (size_t)arow * 128 + ks * 32 + kk);

  int ccol = fl;
  int crow0 = r0 + sub * 4;

  if (CHAIN == 0) {
    #pragma unroll
    for (int cf = 0; cf < 8; ++cf) {
      f32x4 acc = {0.f, 0.f, 0.f, 0.f};
      const unsigned short* wp = Wt + (size_t)(cf * 16 + ccol) * 128 + kk;
      #pragma unroll
      for (int ks = 0; ks < 4; ++ks) {
        bf16x8 b = *reinterpret_cast<const bf16x8*>(wp + ks * 32);
        acc = __builtin_amdgcn_mfma_f32_16x16x32_bf16(af[ks], b, acc, 0, 0, 0);
      }
      float bv = bias[cf * 16 + ccol];
      #pragma unroll
      for (int r = 0; r < 4; ++r) {
        int gr = crow0 + r;
        if (gr < N)
          C[(size_t)gr * 128 + cf * 16 + ccol] = f2bf(fmaxf(acc[r] + bv, 0.f));
      }
    }
  } else {
    unsigned short* my = &sh16[w * 2048];
    #pragma unroll
    for (int cf = 0; cf < 8; ++cf) {
      f32x4 acc = {0.f, 0.f, 0.f, 0.f};
      const unsigned short* wp = Wt + (size_t)(cf * 16 + ccol) * 128 + kk;
      #pragma unroll
      for (int ks = 0; ks < 4; ++ks) {
        bf16x8 b = *reinterpret_cast<const bf16x8*>(wp + ks * 32);
        acc = __builtin_amdgcn_mfma_f32_16x16x32_bf16(af[ks], b, acc, 0, 0, 0);
      }
      float bv = bias[cf * 16 + ccol];
      int col = cf * 16 + ccol;
      int chunk = col >> 3;
      #pragma unroll
      for (int r = 0; r < 4; ++r) {
        int row = sub * 4 + r;
        my[row * 128 + ((chunk ^ row) << 3) + (col & 7)] = f2bf(fmaxf(acc[r] + bv, 0.f));
      }
    }
    // second GEMM: A3 = C2 tile (rows = fl), k-chunks swizzle-read from LDS
    bf16x8 af3[4];
    #pragma unroll
    for (int ks = 0; ks < 4; ++ks) {
      int c = ks * 4 + sub;
      af3[ks] = *reinterpret_cast<const bf16x8*>(&my[fl * 128 + ((c ^ fl) << 3)]);
    }
    #pragma unroll
    for (int cf = 0; cf < 4; ++cf) {                   // FP3=64 cols
      f32x4 acc = {0.f, 0.f, 0.f, 0.f};
      const unsigned short* wp = Wt2 + (size_t)(cf * 16 + ccol) * 128 + kk;
      #pragma unroll
      for (int ks = 0; ks < 4; ++ks) {
        bf16x8 b = *reinterpret_cast<const bf16x8*>(wp + ks * 32);
        acc = __builtin_amdgcn_mfma_f32_16x16x32_bf16(af3[ks], b, acc, 0, 0, 0);
      }
      #pragma unroll
      for (int r = 0; r < 4; ++r) {
        int gr = crow0 + r;
        if (gr < N)
          C[(size_t)gr * 64 + cf * 16 + ccol] = f2bf(acc[r]);
      }
    }
  }
}

extern "C" void kernel_launch(void* const* d_in, const int* in_sizes, int n_in,
                              void* d_out, int out_size, void* d_ws, size_t ws_size,
                              hipStream_t stream) {
  const float* x  = (const float*)d_in[0];
  const void*  ei = d_in[1];
  const float* W0 = (const float*)d_in[2];
  const float* b0 = (const float*)d_in[3];
  const float* W1 = (const float*)d_in[4];
  const float* b1 = (const float*)d_in[5];
  const float* W2 = (const float*)d_in[6];
  const float* b2 = (const float*)d_in[7];
  float* out = (float*)d_out;

  const int N = in_sizes[0] / 128;     // 100000
  const int E = in_sizes[1] / 2;       // 1600000
  const int FOUT = in_sizes[6] / 128;  // 40

  const int NBLKE = (E + EPB - 1) / EPB;        // 196
  const int NBKT  = (N + 255) / 256;            // 391
  const int T     = NBKT * NBLKE;               // 76,636
  const int GS    = (T + 255) / 256;            // 300 (<=1024)

  char* wp = (char*)d_ws;
  auto alloc = [&](size_t bytes) -> void* {
    void* p = (void*)wp;
    wp += (bytes + 255) & ~(size_t)255;
    return p;
  };
  unsigned short* xb   = (unsigned short*)alloc((size_t)N * 128 * 2);
  unsigned short* bufA = (unsigned short*)alloc((size_t)N * 128 * 2);
  unsigned short* bufH = (unsigned short*)alloc((size_t)N * 128 * 2);
  unsigned short* t3   = (unsigned short*)alloc((size_t)N * 64 * 2);
  unsigned short* Wt0  = (unsigned short*)alloc(128 * 128 * 2);
  unsigned short* Wt1  = (unsigned short*)alloc(128 * 128 * 2);
  unsigned short* Wt2  = (unsigned short*)alloc(64 * 128 * 2);
  unsigned* ebuf = (unsigned*)alloc((size_t)E * 4);
  int* colsrc   = (int*)alloc((size_t)E * 4);
  int* rowptr   = (int*)alloc((size_t)(N + 1) * 4);
  int* bhist    = (int*)alloc((size_t)T * 4);
  int* lscan    = (int*)alloc((size_t)T * 4);
  int* scanned  = (int*)alloc((size_t)T * 4);
  int* partials = (int*)alloc(4096);
  int* bucketPtr= (int*)alloc((size_t)(NBKT + 1) * 4);

  long long n4 = (long long)N * 32;
  int ncvt = (int)((n4 + 255) / 256);           // 12500
  int nwt  = (32768 + 8192 + 255) / 256;        // 160

  k_prep<<<NBLKE + ncvt + nwt, 256, 0, stream>>>(ei, E, bhist, NBKT, NBLKE,
                                                 x, xb, n4, ncvt,
                                                 W0, W1, W2, Wt0, Wt1, Wt2, FOUT);
  k_scan_a<<<GS, 256, 0, stream>>>(bhist, lscan, partials, T);
  k_scan_b<<<1, 1024, 0, stream>>>(partials, GS);
  k_scan_c<<<GS, 256, 0, stream>>>(lscan, bhist, partials, scanned, bucketPtr,
                                   T, NBLKE, NBKT, E);
  b_scatter<<<NBLKE, 256, 0, stream>>>(ei, E, scanned, ebuf, NBKT, NBLKE);
  b_pass2<<<NBKT, 256, 0, stream>>>(ebuf, bucketPtr, rowptr, colsrc, N, NBKT, E);

  int gagg = (N + 3) / 4;
  int ggemm = (N + 63) / 64;
  // layer 1: h1 = relu(agg(x)@W0+b0)
  k_agg128b<<<gagg, 256, 0, stream>>>((const unsigned int*)xb, rowptr, colsrc,
                                      (unsigned int*)bufA, N);
  k_gemm<0><<<ggemm, 256, 0, stream>>>(bufA, Wt0, b0, nullptr, bufH, N);
  // layers 2+3a: t3 = relu(agg(h1)@W1+b1) @ W2   (padded to 64 cols)
  k_agg128b<<<gagg, 256, 0, stream>>>((const unsigned int*)bufH, rowptr, colsrc,
                                      (unsigned int*)bufA, N);
  k_gemm<1><<<ggemm, 256, 0, stream>>>(bufA, Wt1, b1, Wt2, t3, N);
  // layer 3b: out = agg(t3) + b2
  k_agg40<<<gagg, 256, 0, stream>>>((const unsigned int*)t3, rowptr, colsrc,
                                    b2, out, N);
}